// Round 1
// baseline (849.466 us; speedup 1.0000x reference)
//
#include <hip/hip_runtime.h>
#include <hip/hip_bf16.h>
#include <math.h>

#define BATCH 16
#define NPTS 10000
#define HID 128
#define NOUT 5
#define TM 64
#define TPB 256

__device__ __forceinline__ float fast_tanh(float x) {
    // tanh(x) = 1 - 2/(exp(2x)+1); exp overflow -> inf -> correct saturation
    float e = __expf(2.0f * x);
    return 1.0f - 2.0f / (e + 1.0f);
}
__device__ __forceinline__ float rowdy_act(float x, float a, float w) {
    return fast_tanh(x) + a * __sinf(w * x);
}

// ---------------- Branch kernel: one block per batch ----------------
// Computes gates (B,4,128), Wcomb[b] = Wtf @ bc[b]^T (128x5), bcomb[b] = btf @ bc[b]^T (5)
__global__ __launch_bounds__(128) void branch_kernel(
    const float* __restrict__ params, const float* __restrict__ Wb0, const float* __restrict__ bb0,
    const float* __restrict__ Wb, const float* __restrict__ bb,
    const float* __restrict__ Wbf, const float* __restrict__ bbf,
    const float* __restrict__ ab, const float* __restrict__ wb,
    const float* __restrict__ Wtf, const float* __restrict__ btf,
    float* __restrict__ g_gates, float* __restrict__ g_wcomb, float* __restrict__ g_bcomb)
{
    const int b = blockIdx.x;
    const int j = threadIdx.x;
    __shared__ float hbuf[HID];
    __shared__ float bcbuf[NOUT][HID];

    // layer 0: params(6) @ Wb0(6,128)
    float z = bb0[j];
    #pragma unroll
    for (int k = 0; k < 6; k++) z += params[b * 6 + k] * Wb0[k * HID + j];
    float h = rowdy_act(z, ab[j], wb[j]);
    float g = h;
    g_gates[b * 4 * HID + 0 * HID + j] = g;
    hbuf[j] = h;
    __syncthreads();

    for (int i = 0; i < 3; i++) {
        const float* W = Wb + i * HID * HID;
        float z0 = 0.f, z1 = 0.f, z2 = 0.f, z3 = 0.f;
        #pragma unroll 8
        for (int k = 0; k < HID; k += 4) {
            z0 += hbuf[k + 0] * W[(k + 0) * HID + j];
            z1 += hbuf[k + 1] * W[(k + 1) * HID + j];
            z2 += hbuf[k + 2] * W[(k + 2) * HID + j];
            z3 += hbuf[k + 3] * W[(k + 3) * HID + j];
        }
        float zz = bb[i * HID + j] + ((z0 + z1) + (z2 + z3));
        float hn = rowdy_act(zz, ab[(i + 1) * HID + j], wb[(i + 1) * HID + j]);
        g += hn;
        g_gates[b * 4 * HID + (i + 1) * HID + j] = g;
        __syncthreads();          // all reads of hbuf done
        hbuf[j] = hn;
        __syncthreads();
    }

    // bc[b][o][j] = branch_out[b][o*128+j] = sum_k h3[k]*Wbf[k][o*128+j] + bbf
    float bo[NOUT];
    #pragma unroll
    for (int o = 0; o < NOUT; o++) bo[o] = bbf[o * HID + j];
    #pragma unroll 4
    for (int k = 0; k < HID; k++) {
        float hv = hbuf[k];
        #pragma unroll
        for (int o = 0; o < NOUT; o++)
            bo[o] += hv * Wbf[k * (HID * NOUT) + o * HID + j];
    }
    #pragma unroll
    for (int o = 0; o < NOUT; o++) bcbuf[o][j] = bo[o];
    __syncthreads();

    // Wcomb[b][k=j][o] = sum_h Wtf[j][h] * bc[o][h]
    float wc[NOUT] = {0.f, 0.f, 0.f, 0.f, 0.f};
    #pragma unroll 4
    for (int h2 = 0; h2 < HID; h2++) {
        float wv = Wtf[j * HID + h2];
        #pragma unroll
        for (int o = 0; o < NOUT; o++) wc[o] += wv * bcbuf[o][h2];
    }
    #pragma unroll
    for (int o = 0; o < NOUT; o++) g_wcomb[b * HID * NOUT + j * NOUT + o] = wc[o];

    if (j < NOUT) {
        float acc = 0.f;
        for (int h2 = 0; h2 < HID; h2++) acc += btf[h2] * bcbuf[j][h2];
        g_bcomb[b * NOUT + j] = acc;
    }
}

// ---------------- Trunk kernel: 64-point tile per block ----------------
__global__ __launch_bounds__(TPB, 2) void trunk_kernel(
    const float* __restrict__ coords, const float* __restrict__ sdf,
    const float* __restrict__ Wt0, const float* __restrict__ bt0,
    const float* __restrict__ Wt, const float* __restrict__ bt,
    const float* __restrict__ at, const float* __restrict__ wt,
    const float* __restrict__ g_gates, const float* __restrict__ g_wcomb,
    const float* __restrict__ g_bcomb,
    float* __restrict__ out)
{
    __shared__ __align__(16) float xbuf[TM][132];     // 132 = 128 + 4 pad (final-stage conflicts)
    __shared__ __align__(16) float Wbuf[32 * HID];    // 32 k-rows staged
    __shared__ float sb_bias[4][HID];
    __shared__ float sb_a[4][HID];
    __shared__ float sb_w[4][HID];
    __shared__ float sb_g[4][HID];
    __shared__ float Wt0s[4][HID];
    __shared__ __align__(16) float Wc[NOUT][HID];     // [o][k] layout
    __shared__ float bcs[NOUT];
    __shared__ float xin[TM][4];
    __shared__ float redbuf[4][TM][NOUT];

    const int b = blockIdx.y;
    const int p0 = blockIdx.x * TM;
    const int tid = threadIdx.x;
    const int tj = tid & 31;         // feature group: cols 4*tj..4*tj+3
    const int tp = tid >> 5;         // point group: rows 8*tp..8*tp+7

    // ---- stage small per-batch / per-layer data ----
    for (int idx = tid; idx < 4 * HID; idx += TPB) {
        int l = idx >> 7, j = idx & (HID - 1);
        sb_bias[l][j] = (l == 0) ? bt0[j] : bt[(l - 1) * HID + j];
        sb_a[l][j] = at[idx];
        sb_w[l][j] = wt[idx];
        sb_g[l][j] = g_gates[b * 4 * HID + idx];
        Wt0s[l][j] = Wt0[idx];       // l doubles as k (both 4x128)
    }
    for (int idx = tid; idx < HID * NOUT; idx += TPB) {
        int k = idx / NOUT, o = idx - k * NOUT;
        Wc[o][k] = g_wcomb[b * HID * NOUT + idx];
    }
    if (tid < NOUT) bcs[tid] = g_bcomb[b * NOUT + tid];

    // ---- stage inputs: cat(coords, sdf) ----
    if (tid < 192) {
        int p = tid / 3, c = tid - p * 3;
        int gp = p0 + p;
        xin[p][c] = (gp < NPTS) ? coords[(b * NPTS + gp) * 3 + c] : 0.0f;
    } else {
        int p = tid - 192;
        int gp = p0 + p;
        xin[p][3] = (gp < NPTS) ? sdf[b * NPTS + gp] : 0.0f;
    }
    __syncthreads();

    float acc[8][4];

    // ---- layer 0 (K=4) ----
    #pragma unroll
    for (int pp = 0; pp < 8; pp++) {
        int p = tp * 8 + pp;
        #pragma unroll
        for (int jj = 0; jj < 4; jj++) {
            int j = 4 * tj + jj;
            float a0 = 0.f;
            #pragma unroll
            for (int k = 0; k < 4; k++) a0 += xin[p][k] * Wt0s[k][j];
            acc[pp][jj] = a0;
        }
    }
    // epilogue l=0
    #pragma unroll
    for (int pp = 0; pp < 8; pp++) {
        #pragma unroll
        for (int jj = 0; jj < 4; jj++) {
            int j = 4 * tj + jj;
            float zv = acc[pp][jj] + sb_bias[0][j];
            acc[pp][jj] = rowdy_act(zv, sb_a[0][j], sb_w[0][j]) * sb_g[0][j];
        }
    }
    __syncthreads();
    #pragma unroll
    for (int pp = 0; pp < 8; pp++) {
        int p = tp * 8 + pp;
        *(float4*)&xbuf[p][4 * tj] = make_float4(acc[pp][0], acc[pp][1], acc[pp][2], acc[pp][3]);
    }

    // ---- layers 1..3: x(64,128) @ Wt[l-1](128,128) ----
    for (int l = 1; l <= 3; l++) {
        const float* Wl = Wt + (l - 1) * HID * HID;
        #pragma unroll
        for (int pp = 0; pp < 8; pp++)
            #pragma unroll
            for (int jj = 0; jj < 4; jj++) acc[pp][jj] = 0.f;

        for (int c = 0; c < 4; c++) {              // 32 k-rows per chunk
            __syncthreads();
            const float4* Wg = (const float4*)(Wl + c * 32 * HID);
            #pragma unroll
            for (int r = 0; r < 4; r++) {
                int f = r * TPB + tid;             // 1024 float4s total
                ((float4*)Wbuf)[f] = Wg[f];
            }
            __syncthreads();
            #pragma unroll
            for (int k4 = 0; k4 < 8; k4++) {
                float4 w0 = *(const float4*)&Wbuf[(k4 * 4 + 0) * HID + 4 * tj];
                float4 w1 = *(const float4*)&Wbuf[(k4 * 4 + 1) * HID + 4 * tj];
                float4 w2 = *(const float4*)&Wbuf[(k4 * 4 + 2) * HID + 4 * tj];
                float4 w3 = *(const float4*)&Wbuf[(k4 * 4 + 3) * HID + 4 * tj];
                #pragma unroll
                for (int pp = 0; pp < 8; pp++) {
                    int p = tp * 8 + pp;
                    float4 xv = *(const float4*)&xbuf[p][c * 32 + k4 * 4];
                    acc[pp][0] += xv.x * w0.x + xv.y * w1.x + xv.z * w2.x + xv.w * w3.x;
                    acc[pp][1] += xv.x * w0.y + xv.y * w1.y + xv.z * w2.y + xv.w * w3.y;
                    acc[pp][2] += xv.x * w0.z + xv.y * w1.z + xv.z * w2.z + xv.w * w3.z;
                    acc[pp][3] += xv.x * w0.w + xv.y * w1.w + xv.z * w2.w + xv.w * w3.w;
                }
            }
        }
        // epilogue: bias + rowdy + gate
        #pragma unroll
        for (int pp = 0; pp < 8; pp++) {
            #pragma unroll
            for (int jj = 0; jj < 4; jj++) {
                int j = 4 * tj + jj;
                float zv = acc[pp][jj] + sb_bias[l][j];
                acc[pp][jj] = rowdy_act(zv, sb_a[l][j], sb_w[l][j]) * sb_g[l][j];
            }
        }
        __syncthreads();             // all reads of xbuf for this layer done
        #pragma unroll
        for (int pp = 0; pp < 8; pp++) {
            int p = tp * 8 + pp;
            *(float4*)&xbuf[p][4 * tj] = make_float4(acc[pp][0], acc[pp][1], acc[pp][2], acc[pp][3]);
        }
    }
    __syncthreads();

    // ---- final: out[p][o] = x(128) . Wcomb[:,o] + bcomb[o], k-split 4 ways ----
    {
        int q = tid & 3, p = tid >> 2;
        float part[NOUT] = {0.f, 0.f, 0.f, 0.f, 0.f};
        #pragma unroll
        for (int k4 = 0; k4 < 8; k4++) {
            float4 xv = *(const float4*)&xbuf[p][q * 32 + k4 * 4];
            #pragma unroll
            for (int o = 0; o < NOUT; o++) {
                float4 wv = *(const float4*)&Wc[o][q * 32 + k4 * 4];
                part[o] += xv.x * wv.x + xv.y * wv.y + xv.z * wv.z + xv.w * wv.w;
            }
        }
        #pragma unroll
        for (int o = 0; o < NOUT; o++) redbuf[q][p][o] = part[o];
    }
    __syncthreads();
    if (tid < TM) {
        int gp = p0 + tid;
        if (gp < NPTS) {
            #pragma unroll
            for (int o = 0; o < NOUT; o++) {
                float s = bcs[o] + redbuf[0][tid][o] + redbuf[1][tid][o]
                                 + redbuf[2][tid][o] + redbuf[3][tid][o];
                out[(size_t)(b * NPTS + gp) * NOUT + o] = s;
            }
        }
    }
}

extern "C" void kernel_launch(void* const* d_in, const int* in_sizes, int n_in,
                              void* d_out, int out_size, void* d_ws, size_t ws_size,
                              hipStream_t stream) {
    (void)in_sizes; (void)n_in; (void)out_size; (void)ws_size;
    const float* coords = (const float*)d_in[0];
    const float* sdf    = (const float*)d_in[1];
    const float* params = (const float*)d_in[2];
    const float* Wb0    = (const float*)d_in[3];
    const float* bb0    = (const float*)d_in[4];
    const float* Wb     = (const float*)d_in[5];
    const float* bb     = (const float*)d_in[6];
    const float* Wbf    = (const float*)d_in[7];
    const float* bbf    = (const float*)d_in[8];
    const float* ab     = (const float*)d_in[9];
    const float* wb     = (const float*)d_in[10];
    const float* Wt0    = (const float*)d_in[11];
    const float* bt0    = (const float*)d_in[12];
    const float* Wt     = (const float*)d_in[13];
    const float* bt     = (const float*)d_in[14];
    const float* Wtf    = (const float*)d_in[15];
    const float* btf    = (const float*)d_in[16];
    const float* at     = (const float*)d_in[17];
    const float* wt     = (const float*)d_in[18];
    float* out = (float*)d_out;
    float* ws  = (float*)d_ws;

    float* g_gates = ws;                    // 16*4*128 = 8192 floats
    float* g_wcomb = ws + 8192;             // 16*128*5 = 10240 floats
    float* g_bcomb = ws + 8192 + 10240;     // 80 floats

    hipLaunchKernelGGL(branch_kernel, dim3(BATCH), dim3(128), 0, stream,
                       params, Wb0, bb0, Wb, bb, Wbf, bbf, ab, wb, Wtf, btf,
                       g_gates, g_wcomb, g_bcomb);

    dim3 grid((NPTS + TM - 1) / TM, BATCH);
    hipLaunchKernelGGL(trunk_kernel, grid, dim3(TPB), 0, stream,
                       coords, sdf, Wt0, bt0, Wt, bt, at, wt,
                       g_gates, g_wcomb, g_bcomb, out);
}

// Round 2
// 446.591 us; speedup vs baseline: 1.9021x; 1.9021x over previous
//
#include <hip/hip_runtime.h>
#include <hip/hip_bf16.h>
#include <math.h>

#define BATCH 16
#define NPTS 10000
#define HID 128
#define NOUT 5
#define TM 64
#define TPB 256

__device__ __forceinline__ float fast_tanh(float x) {
    // tanh(x) = 1 - 2/(exp(2x)+1); exp overflow -> inf -> correct saturation
    float e = __expf(2.0f * x);
    return 1.0f - 2.0f / (e + 1.0f);
}
__device__ __forceinline__ float rowdy_act(float x, float a, float w) {
    return fast_tanh(x) + a * __sinf(w * x);
}

// ---------------- Branch kernel: one block per batch ----------------
// Computes gates (B,4,128), Wcomb[b] = Wtf @ bc[b]^T (128x5), bcomb[b] = btf @ bc[b]^T (5)
__global__ __launch_bounds__(128) void branch_kernel(
    const float* __restrict__ params, const float* __restrict__ Wb0, const float* __restrict__ bb0,
    const float* __restrict__ Wb, const float* __restrict__ bb,
    const float* __restrict__ Wbf, const float* __restrict__ bbf,
    const float* __restrict__ ab, const float* __restrict__ wb,
    const float* __restrict__ Wtf, const float* __restrict__ btf,
    float* __restrict__ g_gates, float* __restrict__ g_wcomb, float* __restrict__ g_bcomb)
{
    const int b = blockIdx.x;
    const int j = threadIdx.x;
    __shared__ float hbuf[HID];
    __shared__ float bcbuf[NOUT][HID];

    // layer 0: params(6) @ Wb0(6,128)
    float z = bb0[j];
    #pragma unroll
    for (int k = 0; k < 6; k++) z += params[b * 6 + k] * Wb0[k * HID + j];
    float h = rowdy_act(z, ab[j], wb[j]);
    float g = h;
    g_gates[b * 4 * HID + 0 * HID + j] = g;
    hbuf[j] = h;
    __syncthreads();

    for (int i = 0; i < 3; i++) {
        const float* W = Wb + i * HID * HID;
        float z0 = 0.f, z1 = 0.f, z2 = 0.f, z3 = 0.f;
        #pragma unroll 8
        for (int k = 0; k < HID; k += 4) {
            z0 += hbuf[k + 0] * W[(k + 0) * HID + j];
            z1 += hbuf[k + 1] * W[(k + 1) * HID + j];
            z2 += hbuf[k + 2] * W[(k + 2) * HID + j];
            z3 += hbuf[k + 3] * W[(k + 3) * HID + j];
        }
        float zz = bb[i * HID + j] + ((z0 + z1) + (z2 + z3));
        float hn = rowdy_act(zz, ab[(i + 1) * HID + j], wb[(i + 1) * HID + j]);
        g += hn;
        g_gates[b * 4 * HID + (i + 1) * HID + j] = g;
        __syncthreads();          // all reads of hbuf done
        hbuf[j] = hn;
        __syncthreads();
    }

    // bc[b][o][j] = branch_out[b][o*128+j] = sum_k h3[k]*Wbf[k][o*128+j] + bbf
    float bo[NOUT];
    #pragma unroll
    for (int o = 0; o < NOUT; o++) bo[o] = bbf[o * HID + j];
    #pragma unroll 4
    for (int k = 0; k < HID; k++) {
        float hv = hbuf[k];
        #pragma unroll
        for (int o = 0; o < NOUT; o++)
            bo[o] += hv * Wbf[k * (HID * NOUT) + o * HID + j];
    }
    #pragma unroll
    for (int o = 0; o < NOUT; o++) bcbuf[o][j] = bo[o];
    __syncthreads();

    // Wcomb[b][k=j][o] = sum_h Wtf[j][h] * bc[o][h]
    float wc[NOUT] = {0.f, 0.f, 0.f, 0.f, 0.f};
    #pragma unroll 4
    for (int h2 = 0; h2 < HID; h2++) {
        float wv = Wtf[j * HID + h2];
        #pragma unroll
        for (int o = 0; o < NOUT; o++) wc[o] += wv * bcbuf[o][h2];
    }
    #pragma unroll
    for (int o = 0; o < NOUT; o++) g_wcomb[b * HID * NOUT + j * NOUT + o] = wc[o];

    if (j < NOUT) {
        float acc = 0.f;
        for (int h2 = 0; h2 < HID; h2++) acc += btf[h2] * bcbuf[j][h2];
        g_bcomb[b * NOUT + j] = acc;
    }
}

// ---------------- Trunk kernel v2: pipelined weight staging, named accumulators ----------------
__global__ __launch_bounds__(TPB, 2) void trunk_kernel(
    const float* __restrict__ coords, const float* __restrict__ sdf,
    const float* __restrict__ Wt0, const float* __restrict__ bt0,
    const float* __restrict__ Wt, const float* __restrict__ bt,
    const float* __restrict__ at, const float* __restrict__ wt,
    const float* __restrict__ g_gates, const float* __restrict__ g_wcomb,
    const float* __restrict__ g_bcomb,
    float* __restrict__ out)
{
    __shared__ __align__(16) float xbuf[TM][132];     // +4 pad
    __shared__ __align__(16) float Wbuf[32 * HID];    // single 16 KB chunk buffer
    __shared__ __align__(16) float sb_bias[4][HID];
    __shared__ __align__(16) float sb_a[4][HID];
    __shared__ __align__(16) float sb_w[4][HID];
    __shared__ __align__(16) float sb_g[4][HID];
    __shared__ __align__(16) float Wt0s[4][HID];
    __shared__ __align__(16) float Wc[NOUT][HID];     // [o][k]
    __shared__ float bcs[NOUT];
    __shared__ __align__(16) float xin[TM][4];
    __shared__ float redbuf[4][TM][NOUT];

    const int b = blockIdx.y;
    const int p0 = blockIdx.x * TM;
    const int tid = threadIdx.x;
    const int tj = tid & 31;         // feature group: cols 4*tj..4*tj+3
    const int tp = tid >> 5;         // point group: rows 8*tp..8*tp+7

    // ---- prefetch weight chunk 0 (layer-1 rows 0..31) into registers, overlap with table staging ----
    const float4* Wg0 = (const float4*)Wt;
    float4 r0 = Wg0[tid];
    float4 r1 = Wg0[TPB + tid];
    float4 r2 = Wg0[2 * TPB + tid];
    float4 r3 = Wg0[3 * TPB + tid];

    // ---- stage small per-batch / per-layer tables ----
    for (int idx = tid; idx < 4 * HID; idx += TPB) {
        int l = idx >> 7, j = idx & (HID - 1);
        sb_bias[l][j] = (l == 0) ? bt0[j] : bt[(l - 1) * HID + j];
        sb_a[l][j] = at[idx];
        sb_w[l][j] = wt[idx];
        sb_g[l][j] = g_gates[b * 4 * HID + idx];
        Wt0s[l][j] = Wt0[idx];       // l doubles as k (both 4x128)
    }
    for (int idx = tid; idx < HID * NOUT; idx += TPB) {
        int k = idx / NOUT, o = idx - k * NOUT;
        Wc[o][k] = g_wcomb[b * HID * NOUT + idx];
    }
    if (tid < NOUT) bcs[tid] = g_bcomb[b * NOUT + tid];

    if (tid < 192) {
        int p = tid / 3, c = tid - p * 3;
        int gp = p0 + p;
        xin[p][c] = (gp < NPTS) ? coords[(size_t)(b * NPTS + gp) * 3 + c] : 0.0f;
    } else {
        int p = tid - 192;
        int gp = p0 + p;
        xin[p][3] = (gp < NPTS) ? sdf[b * NPTS + gp] : 0.0f;
    }
    __syncthreads();

    // ---- layer 0 (K=4) fused with epilogue -> xbuf ----
    {
        float4 t0 = *(const float4*)&Wt0s[0][4 * tj];
        float4 t1 = *(const float4*)&Wt0s[1][4 * tj];
        float4 t2 = *(const float4*)&Wt0s[2][4 * tj];
        float4 t3 = *(const float4*)&Wt0s[3][4 * tj];
        float4 bias4 = *(const float4*)&sb_bias[0][4 * tj];
        float4 aa4 = *(const float4*)&sb_a[0][4 * tj];
        float4 ww4 = *(const float4*)&sb_w[0][4 * tj];
        float4 gg4 = *(const float4*)&sb_g[0][4 * tj];
#define L0STEP(pp) { \
        float4 xi = *(const float4*)&xin[tp * 8 + pp][0]; \
        float4 z; \
        z.x = xi.x * t0.x + xi.y * t1.x + xi.z * t2.x + xi.w * t3.x + bias4.x; \
        z.y = xi.x * t0.y + xi.y * t1.y + xi.z * t2.y + xi.w * t3.y + bias4.y; \
        z.z = xi.x * t0.z + xi.y * t1.z + xi.z * t2.z + xi.w * t3.z + bias4.z; \
        z.w = xi.x * t0.w + xi.y * t1.w + xi.z * t2.w + xi.w * t3.w + bias4.w; \
        z.x = rowdy_act(z.x, aa4.x, ww4.x) * gg4.x; \
        z.y = rowdy_act(z.y, aa4.y, ww4.y) * gg4.y; \
        z.z = rowdy_act(z.z, aa4.z, ww4.z) * gg4.z; \
        z.w = rowdy_act(z.w, aa4.w, ww4.w) * gg4.w; \
        *(float4*)&xbuf[tp * 8 + pp][4 * tj] = z; }
        L0STEP(0) L0STEP(1) L0STEP(2) L0STEP(3)
        L0STEP(4) L0STEP(5) L0STEP(6) L0STEP(7)
#undef L0STEP
    }

    // ---- layers 1..3 as 12 pipelined 32-row chunks ----
    float4 acc0 = make_float4(0.f,0.f,0.f,0.f), acc1 = acc0, acc2 = acc0, acc3 = acc0;
    float4 acc4 = acc0, acc5 = acc0, acc6 = acc0, acc7 = acc0;

    for (int c = 0; c < 12; c++) {
        __syncthreads();                      // (A) prior Wbuf reads + xbuf epilogue writes settled
        ((float4*)Wbuf)[tid]           = r0;  // vmcnt wait lands here, ~1 chunk after issue
        ((float4*)Wbuf)[TPB + tid]     = r1;
        ((float4*)Wbuf)[2 * TPB + tid] = r2;
        ((float4*)Wbuf)[3 * TPB + tid] = r3;
        if (c < 11) {                         // prefetch next chunk; stays in flight through compute
            const float4* Wn = (const float4*)(Wt + (c + 1) * 32 * HID);
            r0 = Wn[tid];
            r1 = Wn[TPB + tid];
            r2 = Wn[2 * TPB + tid];
            r3 = Wn[3 * TPB + tid];
        }
        __syncthreads();                      // (B) Wbuf ready
        const int cb = (c & 3) * 32;
        #pragma unroll
        for (int k4 = 0; k4 < 8; k4++) {
            const int kb = cb + k4 * 4;
            float4 w0 = *(const float4*)&Wbuf[(k4 * 4 + 0) * HID + 4 * tj];
            float4 w1 = *(const float4*)&Wbuf[(k4 * 4 + 1) * HID + 4 * tj];
            float4 w2 = *(const float4*)&Wbuf[(k4 * 4 + 2) * HID + 4 * tj];
            float4 w3 = *(const float4*)&Wbuf[(k4 * 4 + 3) * HID + 4 * tj];
#define FMA1(pp) { \
            float4 xv = *(const float4*)&xbuf[tp * 8 + pp][kb]; \
            acc##pp.x += xv.x * w0.x + xv.y * w1.x + xv.z * w2.x + xv.w * w3.x; \
            acc##pp.y += xv.x * w0.y + xv.y * w1.y + xv.z * w2.y + xv.w * w3.y; \
            acc##pp.z += xv.x * w0.z + xv.y * w1.z + xv.z * w2.z + xv.w * w3.z; \
            acc##pp.w += xv.x * w0.w + xv.y * w1.w + xv.z * w2.w + xv.w * w3.w; }
            FMA1(0) FMA1(1) FMA1(2) FMA1(3)
            FMA1(4) FMA1(5) FMA1(6) FMA1(7)
#undef FMA1
        }
        if ((c & 3) == 3) {
            const int l = (c >> 2) + 1;
            float4 bias4 = *(const float4*)&sb_bias[l][4 * tj];
            float4 aa4 = *(const float4*)&sb_a[l][4 * tj];
            float4 ww4 = *(const float4*)&sb_w[l][4 * tj];
            float4 gg4 = *(const float4*)&sb_g[l][4 * tj];
            __syncthreads();                  // (C) all waves done reading xbuf this layer
#define EPI1(pp) { \
            float4 z = acc##pp; \
            z.x = rowdy_act(z.x + bias4.x, aa4.x, ww4.x) * gg4.x; \
            z.y = rowdy_act(z.y + bias4.y, aa4.y, ww4.y) * gg4.y; \
            z.z = rowdy_act(z.z + bias4.z, aa4.z, ww4.z) * gg4.z; \
            z.w = rowdy_act(z.w + bias4.w, aa4.w, ww4.w) * gg4.w; \
            *(float4*)&xbuf[tp * 8 + pp][4 * tj] = z; \
            acc##pp = make_float4(0.f, 0.f, 0.f, 0.f); }
            EPI1(0) EPI1(1) EPI1(2) EPI1(3)
            EPI1(4) EPI1(5) EPI1(6) EPI1(7)
#undef EPI1
        }
    }
    __syncthreads();

    // ---- final: out[p][o] = x(128) . Wcomb[:,o] + bcomb[o], k-split 4 ways ----
    {
        int q = tid & 3, p = tid >> 2;
        float part0 = 0.f, part1 = 0.f, part2 = 0.f, part3 = 0.f, part4 = 0.f;
        #pragma unroll
        for (int k4 = 0; k4 < 8; k4++) {
            float4 xv = *(const float4*)&xbuf[p][q * 32 + k4 * 4];
            float4 wv0 = *(const float4*)&Wc[0][q * 32 + k4 * 4];
            float4 wv1 = *(const float4*)&Wc[1][q * 32 + k4 * 4];
            float4 wv2 = *(const float4*)&Wc[2][q * 32 + k4 * 4];
            float4 wv3 = *(const float4*)&Wc[3][q * 32 + k4 * 4];
            float4 wv4 = *(const float4*)&Wc[4][q * 32 + k4 * 4];
            part0 += xv.x * wv0.x + xv.y * wv0.y + xv.z * wv0.z + xv.w * wv0.w;
            part1 += xv.x * wv1.x + xv.y * wv1.y + xv.z * wv1.z + xv.w * wv1.w;
            part2 += xv.x * wv2.x + xv.y * wv2.y + xv.z * wv2.z + xv.w * wv2.w;
            part3 += xv.x * wv3.x + xv.y * wv3.y + xv.z * wv3.z + xv.w * wv3.w;
            part4 += xv.x * wv4.x + xv.y * wv4.y + xv.z * wv4.z + xv.w * wv4.w;
        }
        redbuf[q][p][0] = part0;
        redbuf[q][p][1] = part1;
        redbuf[q][p][2] = part2;
        redbuf[q][p][3] = part3;
        redbuf[q][p][4] = part4;
    }
    __syncthreads();
    if (tid < TM) {
        int gp = p0 + tid;
        if (gp < NPTS) {
            #pragma unroll
            for (int o = 0; o < NOUT; o++) {
                float s = bcs[o] + redbuf[0][tid][o] + redbuf[1][tid][o]
                                 + redbuf[2][tid][o] + redbuf[3][tid][o];
                out[(size_t)(b * NPTS + gp) * NOUT + o] = s;
            }
        }
    }
}

extern "C" void kernel_launch(void* const* d_in, const int* in_sizes, int n_in,
                              void* d_out, int out_size, void* d_ws, size_t ws_size,
                              hipStream_t stream) {
    (void)in_sizes; (void)n_in; (void)out_size; (void)ws_size;
    const float* coords = (const float*)d_in[0];
    const float* sdf    = (const float*)d_in[1];
    const float* params = (const float*)d_in[2];
    const float* Wb0    = (const float*)d_in[3];
    const float* bb0    = (const float*)d_in[4];
    const float* Wb     = (const float*)d_in[5];
    const float* bb     = (const float*)d_in[6];
    const float* Wbf    = (const float*)d_in[7];
    const float* bbf    = (const float*)d_in[8];
    const float* ab     = (const float*)d_in[9];
    const float* wb     = (const float*)d_in[10];
    const float* Wt0    = (const float*)d_in[11];
    const float* bt0    = (const float*)d_in[12];
    const float* Wt     = (const float*)d_in[13];
    const float* bt     = (const float*)d_in[14];
    const float* Wtf    = (const float*)d_in[15];
    const float* btf    = (const float*)d_in[16];
    const float* at     = (const float*)d_in[17];
    const float* wt     = (const float*)d_in[18];
    float* out = (float*)d_out;
    float* ws  = (float*)d_ws;

    float* g_gates = ws;                    // 16*4*128 = 8192 floats
    float* g_wcomb = ws + 8192;             // 16*128*5 = 10240 floats
    float* g_bcomb = ws + 8192 + 10240;     // 80 floats

    hipLaunchKernelGGL(branch_kernel, dim3(BATCH), dim3(128), 0, stream,
                       params, Wb0, bb0, Wb, bb, Wbf, bbf, ab, wb, Wtf, btf,
                       g_gates, g_wcomb, g_bcomb);

    dim3 grid((NPTS + TM - 1) / TM, BATCH);
    hipLaunchKernelGGL(trunk_kernel, grid, dim3(TPB), 0, stream,
                       coords, sdf, Wt0, bt0, Wt, bt, at, wt,
                       g_gates, g_wcomb, g_bcomb, out);
}

// Round 3
// 228.172 us; speedup vs baseline: 3.7229x; 1.9573x over previous
//
#include <hip/hip_runtime.h>
#include <hip/hip_bf16.h>
#include <math.h>

#define BATCH 16
#define NPTS 10000
#define HID 128
#define NOUT 5
#define TM 64
#define TPB 256
#define XPAD 8
#define XLD (HID + XPAD)   // 136 ushorts per row; row stride 272 B (16B-aligned)

typedef unsigned short ushort_t;
typedef __attribute__((ext_vector_type(8))) short short8;      // 8 bf16 = 4 VGPRs
typedef __attribute__((ext_vector_type(4))) float f32x4;       // MFMA C/D
typedef __attribute__((ext_vector_type(4))) unsigned short ushort4v;

__device__ __forceinline__ float fast_tanh(float x) {
    float e = __expf(2.0f * x);
    return 1.0f - 2.0f / (e + 1.0f);
}
__device__ __forceinline__ float rowdy_act(float x, float a, float w) {
    return fast_tanh(x) + a * __sinf(w * x);
}
__device__ __forceinline__ ushort_t f32_to_bf16_rn(float f) {
    unsigned u = __float_as_uint(f);
    unsigned r = (u + 0x7FFFu + ((u >> 16) & 1u)) >> 16;
    return (ushort_t)r;
}
__device__ __forceinline__ float bf16_to_f32(ushort_t u) {
    return __uint_as_float(((unsigned)u) << 16);
}
__device__ __forceinline__ void split_bf16(float x, ushort_t& hi, ushort_t& lo) {
    hi = f32_to_bf16_rn(x);
    float hf = bf16_to_f32(hi);
    lo = f32_to_bf16_rn(x - hf);
}

// ---------------- Prep: swizzle trunk weights into MFMA B-fragment order, bf16 hi/lo ----------------
// dst element idx = (((l*8 + t)*4 + s)*64 + lane)*8 + j  maps  W[l][k=s*32+(lane>>4)*8+j][n=t*16+(lane&15)]
__global__ __launch_bounds__(256) void prep_weights(
    const float* __restrict__ Wt, ushort_t* __restrict__ whi, ushort_t* __restrict__ wlo)
{
    int idx = blockIdx.x * 256 + threadIdx.x;
    if (idx >= 3 * HID * HID) return;
    int j   = idx & 7;
    int lam = (idx >> 3) & 63;
    int s   = (idx >> 9) & 3;
    int t   = (idx >> 11) & 7;
    int l   = idx >> 14;
    int k = s * 32 + (lam >> 4) * 8 + j;
    int n = t * 16 + (lam & 15);
    float v = Wt[(l * HID + k) * HID + n];
    ushort_t h, lo;
    split_bf16(v, h, lo);
    whi[idx] = h;
    wlo[idx] = lo;
}

// ---------------- Branch kernel: one block per batch ----------------
__global__ __launch_bounds__(128) void branch_kernel(
    const float* __restrict__ params, const float* __restrict__ Wb0, const float* __restrict__ bb0,
    const float* __restrict__ Wb, const float* __restrict__ bb,
    const float* __restrict__ Wbf, const float* __restrict__ bbf,
    const float* __restrict__ ab, const float* __restrict__ wb,
    const float* __restrict__ Wtf, const float* __restrict__ btf,
    float* __restrict__ g_gates, float* __restrict__ g_wcomb, float* __restrict__ g_bcomb)
{
    const int b = blockIdx.x;
    const int j = threadIdx.x;
    __shared__ float hbuf[HID];
    __shared__ float bcbuf[NOUT][HID];

    float z = bb0[j];
    #pragma unroll
    for (int k = 0; k < 6; k++) z += params[b * 6 + k] * Wb0[k * HID + j];
    float h = rowdy_act(z, ab[j], wb[j]);
    float g = h;
    g_gates[b * 4 * HID + 0 * HID + j] = g;
    hbuf[j] = h;
    __syncthreads();

    for (int i = 0; i < 3; i++) {
        const float* W = Wb + i * HID * HID;
        float z0 = 0.f, z1 = 0.f, z2 = 0.f, z3 = 0.f;
        #pragma unroll 8
        for (int k = 0; k < HID; k += 4) {
            z0 += hbuf[k + 0] * W[(k + 0) * HID + j];
            z1 += hbuf[k + 1] * W[(k + 1) * HID + j];
            z2 += hbuf[k + 2] * W[(k + 2) * HID + j];
            z3 += hbuf[k + 3] * W[(k + 3) * HID + j];
        }
        float zz = bb[i * HID + j] + ((z0 + z1) + (z2 + z3));
        float hn = rowdy_act(zz, ab[(i + 1) * HID + j], wb[(i + 1) * HID + j]);
        g += hn;
        g_gates[b * 4 * HID + (i + 1) * HID + j] = g;
        __syncthreads();
        hbuf[j] = hn;
        __syncthreads();
    }

    float bo[NOUT];
    #pragma unroll
    for (int o = 0; o < NOUT; o++) bo[o] = bbf[o * HID + j];
    #pragma unroll 4
    for (int k = 0; k < HID; k++) {
        float hv = hbuf[k];
        #pragma unroll
        for (int o = 0; o < NOUT; o++)
            bo[o] += hv * Wbf[k * (HID * NOUT) + o * HID + j];
    }
    #pragma unroll
    for (int o = 0; o < NOUT; o++) bcbuf[o][j] = bo[o];
    __syncthreads();

    float wc[NOUT] = {0.f, 0.f, 0.f, 0.f, 0.f};
    #pragma unroll 4
    for (int h2 = 0; h2 < HID; h2++) {
        float wv = Wtf[j * HID + h2];
        #pragma unroll
        for (int o = 0; o < NOUT; o++) wc[o] += wv * bcbuf[o][h2];
    }
    #pragma unroll
    for (int o = 0; o < NOUT; o++) g_wcomb[b * HID * NOUT + j * NOUT + o] = wc[o];

    if (j < NOUT) {
        float acc = 0.f;
        for (int h2 = 0; h2 < HID; h2++) acc += btf[h2] * bcbuf[j][h2];
        g_bcomb[b * NOUT + j] = acc;
    }
}

// ---------------- Trunk kernel v3: bf16 MFMA with hi/lo split precision ----------------
__global__ __launch_bounds__(TPB, 3) void trunk_kernel(
    const float* __restrict__ coords, const float* __restrict__ sdf,
    const float* __restrict__ Wt0, const float* __restrict__ bt0,
    const float* __restrict__ bt, const float* __restrict__ at, const float* __restrict__ wt,
    const float* __restrict__ g_gates, const float* __restrict__ g_wcomb,
    const float* __restrict__ g_bcomb,
    const ushort_t* __restrict__ whi, const ushort_t* __restrict__ wlo,
    float* __restrict__ out)
{
    __shared__ __align__(16) ushort_t xhi[TM][XLD];
    __shared__ __align__(16) ushort_t xlo[TM][XLD];
    __shared__ __align__(16) float sb_bias[4][HID];
    __shared__ __align__(16) float sb_a[4][HID];
    __shared__ __align__(16) float sb_w[4][HID];
    __shared__ __align__(16) float sb_g[4][HID];
    __shared__ __align__(16) float Wt0s[4][HID];
    __shared__ __align__(16) float Wc[NOUT][HID];
    __shared__ float bcs[NOUT];
    __shared__ __align__(16) float xin[TM][4];
    __shared__ float redbuf[4][TM][NOUT];

    const int b = blockIdx.y;
    const int p0 = blockIdx.x * TM;
    const int tid = threadIdx.x;

    // ---- stage tables ----
    for (int idx = tid; idx < 4 * HID; idx += TPB) {
        int l = idx >> 7, j = idx & (HID - 1);
        sb_bias[l][j] = (l == 0) ? bt0[j] : bt[(l - 1) * HID + j];
        sb_a[l][j] = at[idx];
        sb_w[l][j] = wt[idx];
        sb_g[l][j] = g_gates[b * 4 * HID + idx];
        Wt0s[l][j] = Wt0[idx];
    }
    for (int idx = tid; idx < HID * NOUT; idx += TPB) {
        int k = idx / NOUT, o = idx - k * NOUT;
        Wc[o][k] = g_wcomb[b * HID * NOUT + idx];
    }
    if (tid < NOUT) bcs[tid] = g_bcomb[b * NOUT + tid];

    if (tid < 192) {
        int p = tid / 3, c = tid - p * 3;
        int gp = p0 + p;
        xin[p][c] = (gp < NPTS) ? coords[(size_t)(b * NPTS + gp) * 3 + c] : 0.0f;
    } else {
        int p = tid - 192;
        int gp = p0 + p;
        xin[p][3] = (gp < NPTS) ? sdf[b * NPTS + gp] : 0.0f;
    }
    __syncthreads();

    // ---- layer 0 (K=4) on VALU, write bf16 hi/lo to LDS ----
    {
        const int tj = tid & 31, tp = tid >> 5;
        float4 t0 = *(const float4*)&Wt0s[0][4 * tj];
        float4 t1 = *(const float4*)&Wt0s[1][4 * tj];
        float4 t2 = *(const float4*)&Wt0s[2][4 * tj];
        float4 t3 = *(const float4*)&Wt0s[3][4 * tj];
        float4 bias4 = *(const float4*)&sb_bias[0][4 * tj];
        float4 aa4 = *(const float4*)&sb_a[0][4 * tj];
        float4 ww4 = *(const float4*)&sb_w[0][4 * tj];
        float4 gg4 = *(const float4*)&sb_g[0][4 * tj];
        #pragma unroll
        for (int pp = 0; pp < 8; pp++) {
            int p = tp * 8 + pp;
            float4 xi = *(const float4*)&xin[p][0];
            float zx = xi.x * t0.x + xi.y * t1.x + xi.z * t2.x + xi.w * t3.x + bias4.x;
            float zy = xi.x * t0.y + xi.y * t1.y + xi.z * t2.y + xi.w * t3.y + bias4.y;
            float zz = xi.x * t0.z + xi.y * t1.z + xi.z * t2.z + xi.w * t3.z + bias4.z;
            float zw = xi.x * t0.w + xi.y * t1.w + xi.z * t2.w + xi.w * t3.w + bias4.w;
            zx = rowdy_act(zx, aa4.x, ww4.x) * gg4.x;
            zy = rowdy_act(zy, aa4.y, ww4.y) * gg4.y;
            zz = rowdy_act(zz, aa4.z, ww4.z) * gg4.z;
            zw = rowdy_act(zw, aa4.w, ww4.w) * gg4.w;
            ushort4v h4, l4;
            ushort_t h, lo;
            split_bf16(zx, h, lo); h4[0] = h; l4[0] = lo;
            split_bf16(zy, h, lo); h4[1] = h; l4[1] = lo;
            split_bf16(zz, h, lo); h4[2] = h; l4[2] = lo;
            split_bf16(zw, h, lo); h4[3] = h; l4[3] = lo;
            *(ushort4v*)&xhi[p][4 * tj] = h4;
            *(ushort4v*)&xlo[p][4 * tj] = l4;
        }
    }
    __syncthreads();

    // ---- layers 1..3 on MFMA 16x16x32 bf16, 3-term split precision ----
    const int w = tid >> 6;          // wave 0..3 -> n-tiles 2w, 2w+1 (cols 32w..32w+31)
    const int lam = tid & 63;
    const int quad = lam >> 4, lq = lam & 15;
    const short8* Wh8 = (const short8*)whi;
    const short8* Wl8 = (const short8*)wlo;
    const f32x4 zero4 = {0.f, 0.f, 0.f, 0.f};

    for (int l = 1; l <= 3; l++) {
        f32x4 acc[4][2];
        #pragma unroll
        for (int mt = 0; mt < 4; mt++) { acc[mt][0] = zero4; acc[mt][1] = zero4; }
        const int fb = (l - 1) * 32;           // 32 fragments (8 t x 4 s) per layer
        #pragma unroll
        for (int s = 0; s < 4; s++) {
            short8 bh0 = Wh8[(size_t)(fb + (2 * w) * 4 + s) * 64 + lam];
            short8 bl0 = Wl8[(size_t)(fb + (2 * w) * 4 + s) * 64 + lam];
            short8 bh1 = Wh8[(size_t)(fb + (2 * w + 1) * 4 + s) * 64 + lam];
            short8 bl1 = Wl8[(size_t)(fb + (2 * w + 1) * 4 + s) * 64 + lam];
            const int k0 = s * 32 + quad * 8;
            #pragma unroll
            for (int mt = 0; mt < 4; mt++) {
                short8 ah = *(const short8*)&xhi[mt * 16 + lq][k0];
                short8 al = *(const short8*)&xlo[mt * 16 + lq][k0];
                acc[mt][0] = __builtin_amdgcn_mfma_f32_16x16x32_bf16(ah, bh0, acc[mt][0], 0, 0, 0);
                acc[mt][0] = __builtin_amdgcn_mfma_f32_16x16x32_bf16(ah, bl0, acc[mt][0], 0, 0, 0);
                acc[mt][0] = __builtin_amdgcn_mfma_f32_16x16x32_bf16(al, bh0, acc[mt][0], 0, 0, 0);
                acc[mt][1] = __builtin_amdgcn_mfma_f32_16x16x32_bf16(ah, bh1, acc[mt][1], 0, 0, 0);
                acc[mt][1] = __builtin_amdgcn_mfma_f32_16x16x32_bf16(ah, bl1, acc[mt][1], 0, 0, 0);
                acc[mt][1] = __builtin_amdgcn_mfma_f32_16x16x32_bf16(al, bh1, acc[mt][1], 0, 0, 0);
            }
        }
        __syncthreads();   // all waves done READING xhi/xlo for this layer
        // epilogue: C layout col=lane&15, row=quad*4+reg (m89-verified)
        const int n0 = 32 * w + lq, n1 = 32 * w + 16 + lq;
        float bb0_ = sb_bias[l][n0], aa0 = sb_a[l][n0], ww0 = sb_w[l][n0], gg0 = sb_g[l][n0];
        float bb1_ = sb_bias[l][n1], aa1 = sb_a[l][n1], ww1 = sb_w[l][n1], gg1 = sb_g[l][n1];
        #pragma unroll
        for (int mt = 0; mt < 4; mt++) {
            #pragma unroll
            for (int r = 0; r < 4; r++) {
                int row = mt * 16 + quad * 4 + r;
                float y0 = rowdy_act(acc[mt][0][r] + bb0_, aa0, ww0) * gg0;
                float y1 = rowdy_act(acc[mt][1][r] + bb1_, aa1, ww1) * gg1;
                ushort_t h, lo;
                split_bf16(y0, h, lo); xhi[row][n0] = h; xlo[row][n0] = lo;
                split_bf16(y1, h, lo); xhi[row][n1] = h; xlo[row][n1] = lo;
            }
        }
        __syncthreads();   // writes visible before next layer / final
    }

    // ---- final: out[p][o] = (hi+lo)(p,:) . Wc[o,:] + bcomb[o], k-split 4 ways ----
    {
        int q = tid & 3, p = tid >> 2;
        float part[NOUT] = {0.f, 0.f, 0.f, 0.f, 0.f};
        #pragma unroll
        for (int k8 = 0; k8 < 4; k8++) {
            int k0 = q * 32 + k8 * 8;
            short8 xh = *(const short8*)&xhi[p][k0];
            short8 xl = *(const short8*)&xlo[p][k0];
            float xv[8];
            #pragma unroll
            for (int i = 0; i < 8; i++)
                xv[i] = bf16_to_f32((ushort_t)xh[i]) + bf16_to_f32((ushort_t)xl[i]);
            #pragma unroll
            for (int o = 0; o < NOUT; o++) {
                float4 wa = *(const float4*)&Wc[o][k0];
                float4 wb4 = *(const float4*)&Wc[o][k0 + 4];
                part[o] += xv[0] * wa.x + xv[1] * wa.y + xv[2] * wa.z + xv[3] * wa.w
                         + xv[4] * wb4.x + xv[5] * wb4.y + xv[6] * wb4.z + xv[7] * wb4.w;
            }
        }
        #pragma unroll
        for (int o = 0; o < NOUT; o++) redbuf[q][p][o] = part[o];
    }
    __syncthreads();
    if (tid < TM) {
        int gp = p0 + tid;
        if (gp < NPTS) {
            #pragma unroll
            for (int o = 0; o < NOUT; o++) {
                float s = bcs[o] + redbuf[0][tid][o] + redbuf[1][tid][o]
                                 + redbuf[2][tid][o] + redbuf[3][tid][o];
                out[(size_t)(b * NPTS + gp) * NOUT + o] = s;
            }
        }
    }
}

extern "C" void kernel_launch(void* const* d_in, const int* in_sizes, int n_in,
                              void* d_out, int out_size, void* d_ws, size_t ws_size,
                              hipStream_t stream) {
    (void)in_sizes; (void)n_in; (void)out_size; (void)ws_size;
    const float* coords = (const float*)d_in[0];
    const float* sdf    = (const float*)d_in[1];
    const float* params = (const float*)d_in[2];
    const float* Wb0    = (const float*)d_in[3];
    const float* bb0    = (const float*)d_in[4];
    const float* Wb     = (const float*)d_in[5];
    const float* bb     = (const float*)d_in[6];
    const float* Wbf    = (const float*)d_in[7];
    const float* bbf    = (const float*)d_in[8];
    const float* ab     = (const float*)d_in[9];
    const float* wb     = (const float*)d_in[10];
    const float* Wt0    = (const float*)d_in[11];
    const float* bt0    = (const float*)d_in[12];
    const float* Wt     = (const float*)d_in[13];
    const float* bt     = (const float*)d_in[14];
    const float* Wtf    = (const float*)d_in[15];
    const float* btf    = (const float*)d_in[16];
    const float* at     = (const float*)d_in[17];
    const float* wt     = (const float*)d_in[18];
    float* out = (float*)d_out;
    float* ws  = (float*)d_ws;

    float* g_gates = ws;                        // 8192 floats
    float* g_wcomb = ws + 8192;                 // 10240 floats
    float* g_bcomb = ws + 8192 + 10240;         // 80 floats
    ushort_t* whi = (ushort_t*)(ws + 18512);    // 49152 bf16 (16B-aligned offset)
    ushort_t* wlo = whi + 3 * HID * HID;        // 49152 bf16

    hipLaunchKernelGGL(prep_weights, dim3(192), dim3(256), 0, stream, Wt, whi, wlo);

    hipLaunchKernelGGL(branch_kernel, dim3(BATCH), dim3(128), 0, stream,
                       params, Wb0, bb0, Wb, bb, Wbf, bbf, ab, wb, Wtf, btf,
                       g_gates, g_wcomb, g_bcomb);

    dim3 grid((NPTS + TM - 1) / TM, BATCH);
    hipLaunchKernelGGL(trunk_kernel, grid, dim3(TPB), 0, stream,
                       coords, sdf, Wt0, bt0, bt, at, wt,
                       g_gates, g_wcomb, g_bcomb, whi, wlo, out);
}

// Round 6
// 204.941 us; speedup vs baseline: 4.1449x; 1.1133x over previous
//
#include <hip/hip_runtime.h>
#include <hip/hip_bf16.h>
#include <math.h>

#define BATCH 16
#define NPTS 10000
#define HID 128
#define NOUT 5
#define TM 64
#define TPB 256

typedef unsigned short ushort_t;
typedef __attribute__((ext_vector_type(8))) short short8;      // 8 bf16 = 4 VGPRs
typedef __attribute__((ext_vector_type(4))) float f32x4;       // MFMA C/D

__device__ __forceinline__ float fast_tanh(float x) {
    float e = __expf(2.0f * x);
    return 1.0f - 2.0f / (e + 1.0f);
}
__device__ __forceinline__ float rowdy_act(float x, float a, float w) {
    return fast_tanh(x) + a * __sinf(w * x);
}
__device__ __forceinline__ ushort_t f32_to_bf16_rn(float f) {
    unsigned u = __float_as_uint(f);
    unsigned r = (u + 0x7FFFu + ((u >> 16) & 1u)) >> 16;
    return (ushort_t)r;
}
__device__ __forceinline__ float bf16_to_f32(ushort_t u) {
    return __uint_as_float(((unsigned)u) << 16);
}

// ============ Fused prep (blocks 0-2) + branch (blocks 3-18) ============
// prep: swizzle trunk weights into MFMA B-fragment order, bf16 hi (RN) + lo (RN of remainder)
//   frag flat idx = (((l*8 + t)*4 + s)*64 + lam)*8 + j
//   maps W[l][k = s*32 + (lam>>4)*8 + j][n = t*16 + (lam&15)]
__global__ __launch_bounds__(256) void prep_branch_kernel(
    const float* __restrict__ Wt, ushort_t* __restrict__ whi, ushort_t* __restrict__ wlo,
    const float* __restrict__ params, const float* __restrict__ Wb0, const float* __restrict__ bb0,
    const float* __restrict__ Wb, const float* __restrict__ bb,
    const float* __restrict__ Wbf, const float* __restrict__ bbf,
    const float* __restrict__ ab, const float* __restrict__ wb,
    const float* __restrict__ Wtf, const float* __restrict__ btf,
    float* __restrict__ g_gates, float* __restrict__ g_wcomb, float* __restrict__ g_bcomb)
{
    __shared__ float smem[HID * HID];          // prep path: one 64KB weight layer
    __shared__ float hbuf[HID];                // branch path
    __shared__ float bcbuf[NOUT][HID];

    const int tid = threadIdx.x;

    if (blockIdx.x < 3) {
        // ---------------- prep: one block per trunk layer ----------------
        const int l = blockIdx.x;
        const float4* src = (const float4*)(Wt + l * HID * HID);
        #pragma unroll
        for (int i = 0; i < 16; i++)
            ((float4*)smem)[i * 256 + tid] = src[i * 256 + tid];
        __syncthreads();
        for (int e = tid; e < 2048; e += 256) {
            int t = e >> 8, s = (e >> 6) & 3, lam = e & 63;
            int k0 = s * 32 + (lam >> 4) * 8;
            int n = t * 16 + (lam & 15);
            short8 h8, l8;
            #pragma unroll
            for (int j = 0; j < 8; j++) {
                float v = smem[(k0 + j) * HID + n];
                ushort_t h = f32_to_bf16_rn(v);
                float rem = v - bf16_to_f32(h);
                h8[j] = (short)h;
                l8[j] = (short)f32_to_bf16_rn(rem);
            }
            ((short8*)whi)[l * 2048 + e] = h8;
            ((short8*)wlo)[l * 2048 + e] = l8;
        }
        return;
    }

    // ---------------- branch: one (logical) block per batch ----------------
    const int b = blockIdx.x - 3;
    const int j = tid & 127;
    const bool act = (tid < 128);

    float z = bb0[j];
    #pragma unroll
    for (int k = 0; k < 6; k++) z += params[b * 6 + k] * Wb0[k * HID + j];
    float h = rowdy_act(z, ab[j], wb[j]);
    float g = h;
    if (act) {
        g_gates[b * 4 * HID + j] = g;
        hbuf[j] = h;
    }
    __syncthreads();

    for (int i = 0; i < 3; i++) {
        const float* W = Wb + i * HID * HID;
        float z0 = 0.f, z1 = 0.f, z2 = 0.f, z3 = 0.f;
        #pragma unroll 8
        for (int k = 0; k < HID; k += 4) {
            z0 += hbuf[k + 0] * W[(k + 0) * HID + j];
            z1 += hbuf[k + 1] * W[(k + 1) * HID + j];
            z2 += hbuf[k + 2] * W[(k + 2) * HID + j];
            z3 += hbuf[k + 3] * W[(k + 3) * HID + j];
        }
        float zz = bb[i * HID + j] + ((z0 + z1) + (z2 + z3));
        float hn = rowdy_act(zz, ab[(i + 1) * HID + j], wb[(i + 1) * HID + j]);
        g += hn;
        if (act) g_gates[b * 4 * HID + (i + 1) * HID + j] = g;
        __syncthreads();
        if (act) hbuf[j] = hn;
        __syncthreads();
    }

    float bo[NOUT];
    #pragma unroll
    for (int o = 0; o < NOUT; o++) bo[o] = bbf[o * HID + j];
    #pragma unroll 4
    for (int k = 0; k < HID; k++) {
        float hv = hbuf[k];
        #pragma unroll
        for (int o = 0; o < NOUT; o++)
            bo[o] += hv * Wbf[k * (HID * NOUT) + o * HID + j];
    }
    if (act) {
        #pragma unroll
        for (int o = 0; o < NOUT; o++) bcbuf[o][j] = bo[o];
    }
    __syncthreads();

    float wc[NOUT] = {0.f, 0.f, 0.f, 0.f, 0.f};
    #pragma unroll 4
    for (int h2 = 0; h2 < HID; h2++) {
        float wv = Wtf[j * HID + h2];
        #pragma unroll
        for (int o = 0; o < NOUT; o++) wc[o] += wv * bcbuf[o][h2];
    }
    if (act) {
        #pragma unroll
        for (int o = 0; o < NOUT; o++) g_wcomb[b * HID * NOUT + j * NOUT + o] = wc[o];
    }
    if (tid < NOUT) {
        float acc = 0.f;
        for (int h2 = 0; h2 < HID; h2++) acc += btf[h2] * bcbuf[tid][h2];
        g_bcomb[b * NOUT + tid] = acc;
    }
}

// ============ Trunk kernel v6: bf16 MFMA 3-term (proven round-3 numerics),
//              A-fragment-order LDS (proven round-4 layout) ============
__global__ __launch_bounds__(TPB, 3) void trunk_kernel(
    const float* __restrict__ coords, const float* __restrict__ sdf,
    const float* __restrict__ Wt0, const float* __restrict__ bt0,
    const float* __restrict__ bt, const float* __restrict__ at, const float* __restrict__ wt,
    const float* __restrict__ g_gates, const float* __restrict__ g_wcomb,
    const float* __restrict__ g_bcomb,
    const ushort_t* __restrict__ whi, const ushort_t* __restrict__ wlo,
    float* __restrict__ out)
{
    // activations in MFMA A-fragment order:
    //   idx = ((mt*4 + s)*64 + lam)*8 + j  <->  x[row = mt*16+(lam&15)][col = s*32+(lam>>4)*8+j]
    __shared__ __align__(16) ushort_t xfh[TM * HID];            // 16 KB bf16 hi (truncated)
    __shared__ __align__(16) ushort_t xfl[TM * HID];            // 16 KB bf16 lo (truncated remainder)
    __shared__ __align__(16) float sb_bias[4][HID];
    __shared__ __align__(16) float sb_a[4][HID];
    __shared__ __align__(16) float sb_w[4][HID];
    __shared__ __align__(16) float sb_g[4][HID];
    __shared__ __align__(16) float Wt0s[4][HID];
    __shared__ __align__(16) float Wc[NOUT][HID];
    __shared__ float bcs[NOUT];
    __shared__ __align__(16) float xin[TM][4];
    __shared__ float redbuf[4][TM][NOUT];

    const int b = blockIdx.y;
    const int p0 = blockIdx.x * TM;
    const int tid = threadIdx.x;
    const int w = tid >> 6;              // wave id = s-group (layer0) / n-group (layers 1-3)
    const int lam = tid & 63;
    const int quad = lam >> 4, lq = lam & 15;

    // ---- stage tables ----
    for (int idx = tid; idx < 4 * HID; idx += TPB) {
        int l = idx >> 7, jj = idx & (HID - 1);
        sb_bias[l][jj] = (l == 0) ? bt0[jj] : bt[(l - 1) * HID + jj];
        sb_a[l][jj] = at[idx];
        sb_w[l][jj] = wt[idx];
        sb_g[l][jj] = g_gates[b * 4 * HID + idx];
        Wt0s[l][jj] = Wt0[idx];
    }
    for (int idx = tid; idx < HID * NOUT; idx += TPB) {
        int k = idx / NOUT, o = idx - k * NOUT;
        Wc[o][k] = g_wcomb[b * HID * NOUT + idx];
    }
    if (tid < NOUT) bcs[tid] = g_bcomb[b * NOUT + tid];

    if (tid < 192) {
        int p = tid / 3, c = tid - p * 3;
        int gp = p0 + p;
        xin[p][c] = (gp < NPTS) ? coords[(size_t)(b * NPTS + gp) * 3 + c] : 0.0f;
    } else {
        int p = tid - 192;
        int gp = p0 + p;
        xin[p][3] = (gp < NPTS) ? sdf[b * NPTS + gp] : 0.0f;
    }
    __syncthreads();

    // ---- layer 0 (K=4) on VALU, write bf16 hi/lo fragments (linear b128 stores) ----
    {
        const int s = w;
        float w0c[8], w1c[8], w2c[8], w3c[8], bc8[8], ac[8], wc8[8], gc[8];
        #pragma unroll
        for (int jj = 0; jj < 8; jj++) {
            int col = s * 32 + quad * 8 + jj;
            w0c[jj] = Wt0s[0][col];
            w1c[jj] = Wt0s[1][col];
            w2c[jj] = Wt0s[2][col];
            w3c[jj] = Wt0s[3][col];
            bc8[jj] = sb_bias[0][col];
            ac[jj] = sb_a[0][col];
            wc8[jj] = sb_w[0][col];
            gc[jj] = sb_g[0][col];
        }
        #pragma unroll
        for (int mt = 0; mt < 4; mt++) {
            int row = mt * 16 + lq;
            float4 xi = *(const float4*)&xin[row][0];
            float y[8];
            #pragma unroll
            for (int jj = 0; jj < 8; jj++) {
                float zv = xi.x * w0c[jj] + xi.y * w1c[jj] + xi.z * w2c[jj] + xi.w * w3c[jj] + bc8[jj];
                y[jj] = rowdy_act(zv, ac[jj], wc8[jj]) * gc[jj];
            }
            uint4 hp, lp;
            unsigned* hpp = (unsigned*)&hp;
            unsigned* lpp = (unsigned*)&lp;
            #pragma unroll
            for (int pr = 0; pr < 4; pr++) {
                unsigned ue = __float_as_uint(y[2 * pr]);
                unsigned uo = __float_as_uint(y[2 * pr + 1]);
                hpp[pr] = (ue >> 16) | (uo & 0xFFFF0000u);
                float le = y[2 * pr] - __uint_as_float(ue & 0xFFFF0000u);
                float lo_ = y[2 * pr + 1] - __uint_as_float(uo & 0xFFFF0000u);
                lpp[pr] = (__float_as_uint(le) >> 16) | (__float_as_uint(lo_) & 0xFFFF0000u);
            }
            *(uint4*)&xfh[((mt * 4 + s) * 64 + lam) * 8] = hp;
            *(uint4*)&xfl[((mt * 4 + s) * 64 + lam) * 8] = lp;
        }
    }
    __syncthreads();

    // ---- layers 1..3 on MFMA 16x16x32 bf16, single accumulator, 3 terms:
    //      acc = xh*Wh + xl*Wh + xh*Wl  (bias in C-init; dropped xl*Wl ~ 2^-15 rel)
    const short8* Wh8 = (const short8*)whi;
    const short8* Wl8 = (const short8*)wlo;
    // epilogue scatter constants (round-4/5 lineage, hi-path validated)
    const int lq3 = lq >> 3;
    const int jlow = lq & 7;
    const int ebase0 = w * 512 + (lq3 * 16 + quad * 4) * 8 + jlow;          // nt = 2w
    const int ebase1 = w * 512 + ((2 + lq3) * 16 + quad * 4) * 8 + jlow;    // nt = 2w+1
    const int n0 = 32 * w + lq, n1 = 32 * w + 16 + lq;

    for (int l = 1; l <= 3; l++) {
        const int fb = (l - 1) * 32;
        float b0 = sb_bias[l][n0], b1 = sb_bias[l][n1];
        f32x4 acc[4][2];
        #pragma unroll
        for (int mt = 0; mt < 4; mt++) {
            acc[mt][0] = (f32x4){b0, b0, b0, b0};
            acc[mt][1] = (f32x4){b1, b1, b1, b1};
        }
        for (int s = 0; s < 4; s++) {
            short8 bh0 = Wh8[(size_t)(fb + (2 * w) * 4 + s) * 64 + lam];
            short8 bl0 = Wl8[(size_t)(fb + (2 * w) * 4 + s) * 64 + lam];
            short8 bh1 = Wh8[(size_t)(fb + (2 * w + 1) * 4 + s) * 64 + lam];
            short8 bl1 = Wl8[(size_t)(fb + (2 * w + 1) * 4 + s) * 64 + lam];
            #pragma unroll
            for (int mt = 0; mt < 4; mt++) {
                short8 ah = *(const short8*)&xfh[((mt * 4 + s) * 64 + lam) * 8];
                short8 al = *(const short8*)&xfl[((mt * 4 + s) * 64 + lam) * 8];
                acc[mt][0] = __builtin_amdgcn_mfma_f32_16x16x32_bf16(ah, bh0, acc[mt][0], 0, 0, 0);
                acc[mt][0] = __builtin_amdgcn_mfma_f32_16x16x32_bf16(al, bh0, acc[mt][0], 0, 0, 0);
                acc[mt][0] = __builtin_amdgcn_mfma_f32_16x16x32_bf16(ah, bl0, acc[mt][0], 0, 0, 0);
                acc[mt][1] = __builtin_amdgcn_mfma_f32_16x16x32_bf16(ah, bh1, acc[mt][1], 0, 0, 0);
                acc[mt][1] = __builtin_amdgcn_mfma_f32_16x16x32_bf16(al, bh1, acc[mt][1], 0, 0, 0);
                acc[mt][1] = __builtin_amdgcn_mfma_f32_16x16x32_bf16(ah, bl1, acc[mt][1], 0, 0, 0);
            }
        }
        __syncthreads();   // all waves done reading xfh/xfl for this layer
        float a0 = sb_a[l][n0], ww0 = sb_w[l][n0], gg0 = sb_g[l][n0];
        float a1 = sb_a[l][n1], ww1 = sb_w[l][n1], gg1 = sb_g[l][n1];
        #pragma unroll
        for (int mt = 0; mt < 4; mt++) {
            #pragma unroll
            for (int r = 0; r < 4; r++) {
                float y0 = rowdy_act(acc[mt][0][r], a0, ww0) * gg0;
                float y1 = rowdy_act(acc[mt][1][r], a1, ww1) * gg1;
                unsigned u0 = __float_as_uint(y0);
                unsigned u1 = __float_as_uint(y1);
                float l0f = y0 - __uint_as_float(u0 & 0xFFFF0000u);
                float l1f = y1 - __uint_as_float(u1 & 0xFFFF0000u);
                xfh[mt * 2048 + ebase0 + r * 8] = (ushort_t)(u0 >> 16);
                xfl[mt * 2048 + ebase0 + r * 8] = (ushort_t)(__float_as_uint(l0f) >> 16);
                xfh[mt * 2048 + ebase1 + r * 8] = (ushort_t)(u1 >> 16);
                xfl[mt * 2048 + ebase1 + r * 8] = (ushort_t)(__float_as_uint(l1f) >> 16);
            }
        }
        __syncthreads();
    }

    // ---- final: out[p][o] = (hi+lo)(p,:) . Wc[o,:] + bcomb[o], k-split 4 ways ----
    {
        int q = tid & 3, p = tid >> 2;
        int mt = p >> 4, prow = p & 15;
        float part[NOUT] = {0.f, 0.f, 0.f, 0.f, 0.f};
        #pragma unroll
        for (int g8 = 0; g8 < 4; g8++) {
            int base = ((mt * 4 + q) * 64 + g8 * 16 + prow) * 8;
            uint4 h4 = *(const uint4*)&xfh[base];
            uint4 l4 = *(const uint4*)&xfl[base];
            const unsigned* hu = (const unsigned*)&h4;
            const unsigned* lu = (const unsigned*)&l4;
            int c0 = q * 32 + g8 * 8;
            float xv[8];
            #pragma unroll
            for (int pr = 0; pr < 4; pr++) {
                xv[2 * pr]     = __uint_as_float(hu[pr] << 16) + __uint_as_float(lu[pr] << 16);
                xv[2 * pr + 1] = __uint_as_float(hu[pr] & 0xFFFF0000u) + __uint_as_float(lu[pr] & 0xFFFF0000u);
            }
            #pragma unroll
            for (int o = 0; o < NOUT; o++) {
                float4 wa = *(const float4*)&Wc[o][c0];
                float4 wb4 = *(const float4*)&Wc[o][c0 + 4];
                part[o] += xv[0] * wa.x + xv[1] * wa.y + xv[2] * wa.z + xv[3] * wa.w
                         + xv[4] * wb4.x + xv[5] * wb4.y + xv[6] * wb4.z + xv[7] * wb4.w;
            }
        }
        #pragma unroll
        for (int o = 0; o < NOUT; o++) redbuf[q][p][o] = part[o];
    }
    __syncthreads();
    if (tid < TM) {
        int gp = p0 + tid;
        if (gp < NPTS) {
            #pragma unroll
            for (int o = 0; o < NOUT; o++) {
                float s = bcs[o] + redbuf[0][tid][o] + redbuf[1][tid][o]
                                 + redbuf[2][tid][o] + redbuf[3][tid][o];
                out[(size_t)(b * NPTS + gp) * NOUT + o] = s;
            }
        }
    }
}

extern "C" void kernel_launch(void* const* d_in, const int* in_sizes, int n_in,
                              void* d_out, int out_size, void* d_ws, size_t ws_size,
                              hipStream_t stream) {
    (void)in_sizes; (void)n_in; (void)out_size; (void)ws_size;
    const float* coords = (const float*)d_in[0];
    const float* sdf    = (const float*)d_in[1];
    const float* params = (const float*)d_in[2];
    const float* Wb0    = (const float*)d_in[3];
    const float* bb0    = (const float*)d_in[4];
    const float* Wb     = (const float*)d_in[5];
    const float* bb     = (const float*)d_in[6];
    const float* Wbf    = (const float*)d_in[7];
    const float* bbf    = (const float*)d_in[8];
    const float* ab     = (const float*)d_in[9];
    const float* wb     = (const float*)d_in[10];
    const float* Wt0    = (const float*)d_in[11];
    const float* bt0    = (const float*)d_in[12];
    const float* Wt     = (const float*)d_in[13];
    const float* bt     = (const float*)d_in[14];
    const float* Wtf    = (const float*)d_in[15];
    const float* btf    = (const float*)d_in[16];
    const float* at     = (const float*)d_in[17];
    const float* wt     = (const float*)d_in[18];
    float* out = (float*)d_out;
    float* ws  = (float*)d_ws;

    float* g_gates = ws;                        // 8192 floats
    float* g_wcomb = ws + 8192;                 // 10240 floats
    float* g_bcomb = ws + 8192 + 10240;         // 80 floats
    ushort_t* whi = (ushort_t*)(ws + 18512);    // 49152 bf16
    ushort_t* wlo = whi + 3 * HID * HID;        // 49152 bf16

    hipLaunchKernelGGL(prep_branch_kernel, dim3(19), dim3(256), 0, stream,
                       Wt, whi, wlo,
                       params, Wb0, bb0, Wb, bb, Wbf, bbf, ab, wb, Wtf, btf,
                       g_gates, g_wcomb, g_bcomb);

    dim3 grid((NPTS + TM - 1) / TM, BATCH);
    hipLaunchKernelGGL(trunk_kernel, grid, dim3(TPB), 0, stream,
                       coords, sdf, Wt0, bt0, bt, at, wt,
                       g_gates, g_wcomb, g_bcomb, whi, wlo, out);
}